// Round 1
// baseline (816.723 us; speedup 1.0000x reference)
//
#include <hip/hip_runtime.h>
#include <stdint.h>

// Problem constants (fixed by reference: x_in (32, 4096, 512) fp32)
#define T_LEN 4096
#define C_LEN 512
#define B_LEN 32
#define W_LEN 2055              // floor((T + 16 - 1)/2)
#define ROWS (B_LEN * C_LEN)    // 16384

// db8 decomposition low-pass filter (float32-rounded from the float64 literals,
// matching np .astype(np.float32))
__device__ __constant__ float c_dec_lo[16] = {
    (float)-0.00011747678400228192, (float)0.0006754494059985568,
    (float)-0.0003917403729959771,  (float)-0.00487035299301066,
    (float)0.008746094047015655,    (float)0.013981027917015516,
    (float)-0.04408825393106472,    (float)-0.01736930100202211,
    (float)0.128747426620186,       (float)0.00047248457399797254,
    (float)-0.2840155429624281,     (float)-0.015829105256023893,
    (float)0.5853546836548691,      (float)0.6756307362980128,
    (float)0.3128715909144659,      (float)0.05441584224308161};

// Symmetric extension: E[j], j in [0, T+29] -> x index.
// E = [x14..x0 | x0..x_{T-1} | x_{T-1}..x_{T-15}]
__device__ __forceinline__ int sym_idx(int j) {
  int t = j - 15;
  if (t < 0) t = -1 - t;                 // j<15 -> 14-j
  if (t >= T_LEN) t = 2 * T_LEN - 1 - t; // tail reflection
  return t;
}

// ---------------------------------------------------------------------------
// K1: DWT.  low[n] = sum_u DEC_LO[u] * E[2n+16-u]; high with DEC_HI.
// DEC_HI[u] = (u odd ? +1 : -1) * DEC_LO[15-u]
// Block: 256 thr, handles (b, 64-channel tile, 32-w tile).
// ---------------------------------------------------------------------------
#define K1_WT 32
#define K1_CT 64
#define K1_JEXT (2 * K1_WT + 14) // 78 extended samples needed per 32 outputs

__global__ __launch_bounds__(256) void k_dwt(const float* __restrict__ x,
                                             float* __restrict__ lo,
                                             float* __restrict__ hi) {
  __shared__ float lds[K1_JEXT * K1_CT]; // 78*64 floats; reused as 64x33 stage
  const int w0 = blockIdx.x * K1_WT;
  const int bc = blockIdx.y; // 0..255 = 32 b * 8 ctiles
  const int b = bc >> 3;
  const int c0 = (bc & 7) * K1_CT;
  const int tid = threadIdx.x;
  const int jlo = 2 * w0 + 1;

  // Phase 1: stage E tile [78 j][64 c], coalesced along c
  for (int r = tid; r < K1_JEXT * K1_CT; r += 256) {
    int jj = r >> 6;
    int c = r & 63;
    int j = jlo + jj;
    if (j > T_LEN + 29) j = T_LEN + 29; // partial last tile: clamp (unused)
    int t = sym_idx(j);
    lds[r] = x[((size_t)b * T_LEN + t) * C_LEN + c0 + c];
  }
  __syncthreads();

  // Phase 2: each thread computes 8 w's for one channel
  const int c = tid & 63;
  const int wq = tid >> 6; // 0..3
  float rlo[8], rhi[8];
#pragma unroll
  for (int k = 0; k < 8; ++k) {
    const int wi = wq * 8 + k;
    float accl = 0.f, acch = 0.f;
#pragma unroll
    for (int u = 0; u < 16; ++u) {
      float e = lds[(2 * wi + 15 - u) * 64 + c]; // j-jlo = 2wi+15-u
      float dl = c_dec_lo[u];
      float dh = (u & 1) ? c_dec_lo[15 - u] : -c_dec_lo[15 - u];
      accl = fmaf(dl, e, accl);
      acch = fmaf(dh, e, acch);
    }
    rlo[k] = accl;
    rhi[k] = acch;
  }

  // Phase 3: LDS transpose-stage, coalesced writes along w
  const int wlim = W_LEN - w0; // <32 only on last tile
  for (int pass = 0; pass < 2; ++pass) {
    __syncthreads();
#pragma unroll
    for (int k = 0; k < 8; ++k)
      lds[c * 33 + wq * 8 + k] = pass ? rhi[k] : rlo[k]; // stride-33: 2-way max
    __syncthreads();
    float* dst = pass ? hi : lo;
    for (int r = tid; r < K1_CT * K1_WT; r += 256) {
      int cc = r >> 5;
      int ww = r & 31;
      if (ww < wlim)
        dst[(size_t)(b * C_LEN + c0 + cc) * W_LEN + w0 + ww] = lds[cc * 33 + ww];
    }
  }
}

// ---------------------------------------------------------------------------
// K2: per-row quantile threshold via 4-pass radix select on float bit patterns
// (squares are >=0, so uint order == float order). Matches jnp.quantile
// 'linear': pos=q*(W-1); thr = a[floor]*(1-g) + a[ceil]*g, g=pos-floor(pos).
// One block (256 thr) per row.
// ---------------------------------------------------------------------------
__global__ __launch_bounds__(256) void k_thresh(const float* __restrict__ hi,
                                                const float* __restrict__ qp,
                                                float* __restrict__ thr) {
  __shared__ uint32_t keys[W_LEN];
  __shared__ int hist[256];
  __shared__ int scan[256];
  __shared__ int s_bin, s_kk, s_cnt;
  __shared__ uint32_t s_minv;
  const int row = blockIdx.x;
  const int tid = threadIdx.x;

  const float q = qp[0];
  float pos = __fmul_rn(q, (float)(W_LEN - 1));
  if (pos < 0.f) pos = 0.f;
  if (pos > (float)(W_LEN - 1)) pos = (float)(W_LEN - 1);
  const int lo_i = (int)floorf(pos);
  const int hi_i = (int)ceilf(pos);
  const float gw = pos - floorf(pos); // high weight (lax.sub)
  const float lw = 1.0f - gw;

  for (int w = tid; w < W_LEN; w += 256) {
    float h = hi[(size_t)row * W_LEN + w];
    keys[w] = __float_as_uint(__fmul_rn(h, h)); // high_s = high**2 (fp32 mul)
  }
  if (tid == 0) s_kk = lo_i;
  __syncthreads();

  uint32_t prefix = 0;
  for (int shift = 24; shift >= 0; shift -= 8) {
    hist[tid] = 0;
    __syncthreads();
    uint32_t msk = (shift == 24) ? 0u : (0xFFFFFFFFu << (shift + 8));
    for (int w = tid; w < W_LEN; w += 256) {
      uint32_t key = keys[w];
      if ((key & msk) == prefix) atomicAdd(&hist[(key >> shift) & 255], 1);
    }
    __syncthreads();
    // inclusive Hillis-Steele scan of hist -> scan
    scan[tid] = hist[tid];
    __syncthreads();
    for (int d = 1; d < 256; d <<= 1) {
      int t = (tid >= d) ? scan[tid - d] : 0;
      __syncthreads();
      if (tid >= d) scan[tid] += t;
      __syncthreads();
    }
    int kk = s_kk;
    __syncthreads(); // everyone has read old s_kk before the winner rewrites it
    int incl = scan[tid];
    int excl = (tid == 0) ? 0 : scan[tid - 1];
    if (kk >= excl && kk < incl) {
      s_bin = tid;
      s_kk = kk - excl;
    }
    __syncthreads();
    prefix |= ((uint32_t)s_bin) << shift;
  }
  const float a_lo = __uint_as_float(prefix);

  float a_hi_v;
  if (hi_i == lo_i) {
    a_hi_v = a_lo;
  } else {
    if (tid == 0) {
      s_cnt = 0;
      s_minv = 0xFFFFFFFFu;
    }
    __syncthreads();
    int cnt = 0;
    uint32_t mn = 0xFFFFFFFFu;
    for (int w = tid; w < W_LEN; w += 256) {
      uint32_t key = keys[w];
      if (key <= prefix)
        cnt++;
      else
        mn = min(mn, key);
    }
    atomicAdd(&s_cnt, cnt);
    atomicMin(&s_minv, mn);
    __syncthreads();
    // rank lo_i+1 value: duplicate of a_lo if enough keys <= a_lo, else next-up
    a_hi_v = (s_cnt >= lo_i + 2) ? a_lo : __uint_as_float(s_minv);
  }

  if (tid == 0)
    thr[row] = __fadd_rn(__fmul_rn(a_lo, lw), __fmul_rn(a_hi_v, gw));
}

// ---------------------------------------------------------------------------
// K3: mask + IDWT + transpose-out.
// rec[s] = sum_{u == s mod 2} REC_LO[u]*ca[(s+14-u)/2] + REC_HI[u]*cdm[...]
// REC_LO[u]=DEC_LO[15-u]; REC_HI[u]=(u odd ? -1:+1)*DEC_LO[u].
// For T=4096 all coeff indices stay in [0,2054] -> no bounds checks.
// Block: 256 thr, (b, 64-c tile, 64-s tile). Writes: lane=c -> 256B/wave.
// ---------------------------------------------------------------------------
#define K3_MT 39 // coeffs needed for 64 outputs: (63+14-1)/2 + 1

__global__ __launch_bounds__(256) void k_idwt(const float* __restrict__ lo,
                                              const float* __restrict__ hi,
                                              const float* __restrict__ thr,
                                              float* __restrict__ out) {
  __shared__ float s_ca[K3_MT * 65]; // pitch 65: conflict-free load & compute
  __shared__ float s_cd[K3_MT * 65];
  __shared__ float s_thr[64];
  const int s0 = blockIdx.x * 64;
  const int bc = blockIdx.y;
  const int b = bc >> 3;
  const int c0 = (bc & 7) * 64;
  const int m0 = s0 >> 1;
  const int tid = threadIdx.x;

  if (tid < 64) s_thr[tid] = thr[b * C_LEN + c0 + tid];
  __syncthreads();

  for (int r = tid; r < K3_MT * 64; r += 256) {
    int cc = r / K3_MT;
    int mm = r - cc * K3_MT;
    size_t base = (size_t)(b * C_LEN + c0 + cc) * W_LEN + m0 + mm;
    s_ca[mm * 65 + cc] = lo[base];
    float cd = hi[base];
    float sq = __fmul_rn(cd, cd);
    s_cd[mm * 65 + cc] = (sq > s_thr[cc]) ? cd : 0.0f; // strict >, matches ref
  }
  __syncthreads();

  const int c = tid & 63;
  const int sg = tid >> 6; // 0..3, each thread does 16 consecutive s
#pragma unroll
  for (int k = 0; k < 16; ++k) {
    int ss = sg * 16 + k;
    int par = ss & 1;
    float acc = 0.f;
#pragma unroll
    for (int j = 0; j < 8; ++j) {
      int u = 2 * j + par;
      int mm = (ss + 14 - u) >> 1;
      float rl = c_dec_lo[15 - u];
      float rh = (u & 1) ? -c_dec_lo[u] : c_dec_lo[u];
      acc = fmaf(rl, s_ca[mm * 65 + c], acc);
      acc = fmaf(rh, s_cd[mm * 65 + c], acc);
    }
    out[((size_t)b * T_LEN + s0 + ss) * C_LEN + c0 + c] = acc;
  }
}

// ---------------------------------------------------------------------------
extern "C" void kernel_launch(void* const* d_in, const int* in_sizes, int n_in,
                              void* d_out, int out_size, void* d_ws,
                              size_t ws_size, hipStream_t stream) {
  const float* x = (const float*)d_in[0];
  const float* qp = (const float*)d_in[1];
  float* out = (float*)d_out;

  // workspace layout: low | high | thr  (needs ~270 MB)
  float* lo = (float*)d_ws;
  float* hi = lo + (size_t)ROWS * W_LEN;
  float* thr = hi + (size_t)ROWS * W_LEN;

  dim3 g1((W_LEN + K1_WT - 1) / K1_WT, B_LEN * (C_LEN / K1_CT)); // 65 x 256
  k_dwt<<<g1, 256, 0, stream>>>(x, lo, hi);

  k_thresh<<<dim3(ROWS), 256, 0, stream>>>(hi, qp, thr);

  dim3 g3(T_LEN / 64, B_LEN * (C_LEN / 64)); // 64 x 256
  k_idwt<<<g3, 256, 0, stream>>>(lo, hi, thr, out);
}

// Round 2
// 698.293 us; speedup vs baseline: 1.1696x; 1.1696x over previous
//
#include <hip/hip_runtime.h>
#include <stdint.h>

// Problem constants (fixed by reference: x_in (32, 4096, 512) fp32)
#define T_LEN 4096
#define C_LEN 512
#define B_LEN 32
#define W_LEN 2055           // floor((T + 16 - 1)/2)
#define W_PITCH 2064         // padded: rows 64B-aligned (2064*4 = 8256 = 129*64)
#define ROWS (B_LEN * C_LEN) // 16384

// db8 decomposition low-pass filter (float32-rounded)
__device__ __constant__ float c_dec_lo[16] = {
    (float)-0.00011747678400228192, (float)0.0006754494059985568,
    (float)-0.0003917403729959771,  (float)-0.00487035299301066,
    (float)0.008746094047015655,    (float)0.013981027917015516,
    (float)-0.04408825393106472,    (float)-0.01736930100202211,
    (float)0.128747426620186,       (float)0.00047248457399797254,
    (float)-0.2840155429624281,     (float)-0.015829105256023893,
    (float)0.5853546836548691,      (float)0.6756307362980128,
    (float)0.3128715909144659,      (float)0.05441584224308161};

// Symmetric extension: E[j] -> x index. E = [x14..x0 | x0..x_{T-1} | x_{T-1}..]
__device__ __forceinline__ int sym_idx(int j) {
  int t = j - 15;
  if (t < 0) t = -1 - t;
  if (t >= T_LEN) t = 2 * T_LEN - 1 - t;
  return t;
}

// ---------------------------------------------------------------------------
// K1: DWT. low[n] = sum_u DEC_LO[u] * E[2n+16-u]; DEC_HI[u]=(u odd?+:-)DEC_LO[15-u]
// Block: 256 thr, (b, 64-channel tile, 32-w tile). float4 loads/stores.
// ---------------------------------------------------------------------------
#define K1_WT 32
#define K1_JEXT (2 * K1_WT + 14) // 78
#define K1_PITCH 68              // float4-aligned, staggers banks across j

__global__ __launch_bounds__(256) void k_dwt(const float* __restrict__ x,
                                             float* __restrict__ lo,
                                             float* __restrict__ hi) {
  __shared__ float lds[K1_JEXT * K1_PITCH]; // 21216 B; reused as 64x33 stage
  const int w0 = blockIdx.x * K1_WT;
  const int bc = blockIdx.y;
  const int b = bc >> 3;
  const int c0 = (bc & 7) * 64;
  const int tid = threadIdx.x;
  const int jlo = 2 * w0 + 1;

  // Phase 1: stage E tile [78 j][64 c] with float4 loads (coalesced along c)
  for (int r = tid; r < K1_JEXT * 16; r += 256) {
    int jj = r >> 4;
    int c4 = (r & 15) * 4;
    int t = sym_idx(jlo + jj);
    float4 v = *(const float4*)(x + ((size_t)b * T_LEN + t) * C_LEN + c0 + c4);
    *(float4*)&lds[jj * K1_PITCH + c4] = v;
  }
  __syncthreads();

  // Phase 2: each thread computes 8 w's for one channel
  const int c = tid & 63;
  const int wq = tid >> 6; // 0..3
  float rlo[8], rhi[8];
#pragma unroll
  for (int k = 0; k < 8; ++k) {
    const int wi = wq * 8 + k;
    float accl = 0.f, acch = 0.f;
#pragma unroll
    for (int u = 0; u < 16; ++u) {
      float e = lds[(2 * wi + 15 - u) * K1_PITCH + c];
      float dl = c_dec_lo[u];
      float dh = (u & 1) ? c_dec_lo[15 - u] : -c_dec_lo[15 - u];
      accl = fmaf(dl, e, accl);
      acch = fmaf(dh, e, acch);
    }
    rlo[k] = accl;
    rhi[k] = acch;
  }

  // Phase 3: transpose through LDS (pitch 33: 2-way max), float4 stores
  const int wlim = W_LEN - w0; // <32 only on last tile
  float* st = lds;             // alias: phase-2 reads are done before the sync
  for (int pass = 0; pass < 2; ++pass) {
    __syncthreads();
#pragma unroll
    for (int k = 0; k < 8; ++k)
      st[c * 33 + wq * 8 + k] = pass ? rhi[k] : rlo[k];
    __syncthreads();
    float* dst = pass ? hi : lo;
    for (int r = tid; r < 64 * 8; r += 256) {
      int cc = r >> 3;
      int w4 = (r & 7) * 4;
      size_t base = (size_t)(b * C_LEN + c0 + cc) * W_PITCH + w0 + w4;
      if (w4 + 3 < wlim) {
        float4 v = {st[cc * 33 + w4], st[cc * 33 + w4 + 1],
                    st[cc * 33 + w4 + 2], st[cc * 33 + w4 + 3]};
        *(float4*)(dst + base) = v;
      } else {
#pragma unroll
        for (int i = 0; i < 4; ++i)
          if (w4 + i < wlim) dst[base + i] = st[cc * 33 + w4 + i];
      }
    }
  }
}

// ---------------------------------------------------------------------------
// K2: per-row quantile via 3-pass radix select (11/11/10-bit digits) on float
// bit patterns (squares >=0 so uint order == float order). Block per row.
// Histogram stored swizzled: bin -> (bin&7)*256 + (bin>>3) so the scan's
// 8-bins-per-thread reads are conflict-free. Wave scans via shfl.
// ---------------------------------------------------------------------------
__global__ __launch_bounds__(256) void k_thresh(const float* __restrict__ hi,
                                                const float* __restrict__ qp,
                                                float* __restrict__ thr) {
  __shared__ uint32_t keys[2056];
  __shared__ uint32_t hist[2048];
  __shared__ uint32_t s_wsum[4];
  __shared__ int s_bin, s_kk, s_cnt;
  __shared__ uint32_t s_minv;
  const int row = blockIdx.x;
  const int tid = threadIdx.x;
  const int lane = tid & 63;
  const int wv = tid >> 6;

  const float q = qp[0];
  float pos = __fmul_rn(q, (float)(W_LEN - 1));
  if (pos < 0.f) pos = 0.f;
  if (pos > (float)(W_LEN - 1)) pos = (float)(W_LEN - 1);
  const int lo_i = (int)floorf(pos);
  const int hi_i = (int)ceilf(pos);
  const float gw = pos - floorf(pos);
  const float lw = 1.0f - gw;

  // stage squared keys (float4 loads; rows are 16B-aligned at pitch 2064)
  const float* rowp = hi + (size_t)row * W_PITCH;
  for (int r = tid; r < 513; r += 256) { // 513*4 = 2052
    float4 v = *(const float4*)(rowp + r * 4);
    keys[r * 4 + 0] = __float_as_uint(__fmul_rn(v.x, v.x));
    keys[r * 4 + 1] = __float_as_uint(__fmul_rn(v.y, v.y));
    keys[r * 4 + 2] = __float_as_uint(__fmul_rn(v.z, v.z));
    keys[r * 4 + 3] = __float_as_uint(__fmul_rn(v.w, v.w));
  }
  if (tid < 3) {
    float h = rowp[2052 + tid];
    keys[2052 + tid] = __float_as_uint(__fmul_rn(h, h));
  }

  int kk = lo_i;
  uint32_t pref = 0;
  const int shifts[3] = {21, 10, 0};
  const uint32_t cmask[3] = {0u, 0xFFE00000u, 0xFFFFFC00u};
  const uint32_t dmask[3] = {0x7FFu, 0x7FFu, 0x3FFu};

#pragma unroll
  for (int p = 0; p < 3; ++p) {
    const int shift = shifts[p];
    for (int r = tid; r < 2048; r += 256) hist[r] = 0;
    __syncthreads();
    for (int r = tid; r < W_LEN; r += 256) {
      uint32_t key = keys[r];
      if ((key & cmask[p]) == (pref & cmask[p])) {
        uint32_t d = (key >> shift) & dmask[p];
        atomicAdd(&hist[((d & 7) << 8) + (d >> 3)], 1u);
      }
    }
    __syncthreads();
    // scan: each thread owns 8 consecutive bins
    uint32_t c8[8];
    uint32_t sum8 = 0;
#pragma unroll
    for (int i = 0; i < 8; ++i) {
      c8[i] = hist[i * 256 + tid];
      sum8 += c8[i];
    }
    uint32_t incl = sum8;
#pragma unroll
    for (int d = 1; d < 64; d <<= 1) {
      uint32_t v = (uint32_t)__shfl_up((int)incl, d);
      if (lane >= d) incl += v;
    }
    if (lane == 63) s_wsum[wv] = incl;
    __syncthreads();
    uint32_t excl = incl - sum8;
    for (int w = 0; w < wv; ++w) excl += s_wsum[w];
    if ((uint32_t)kk >= excl && (uint32_t)kk < excl + sum8) {
      int k2 = kk - (int)excl;
      int i = 0;
      while (i < 7 && k2 >= (int)c8[i]) {
        k2 -= (int)c8[i];
        ++i;
      }
      s_bin = tid * 8 + i;
      s_kk = k2;
    }
    __syncthreads();
    pref |= ((uint32_t)s_bin) << shift;
    kk = s_kk;
  }
  const float a_lo = __uint_as_float(pref);

  float a_hi_v;
  if (hi_i == lo_i) {
    a_hi_v = a_lo;
  } else {
    if (tid == 0) {
      s_cnt = 0;
      s_minv = 0xFFFFFFFFu;
    }
    __syncthreads();
    int cnt = 0;
    uint32_t mn = 0xFFFFFFFFu;
    for (int r = tid; r < W_LEN; r += 256) {
      uint32_t key = keys[r];
      if (key <= pref)
        cnt++;
      else
        mn = min(mn, key);
    }
    atomicAdd(&s_cnt, cnt);
    atomicMin(&s_minv, mn);
    __syncthreads();
    a_hi_v = (s_cnt >= lo_i + 2) ? a_lo : __uint_as_float(s_minv);
  }

  if (tid == 0)
    thr[row] = __fadd_rn(__fmul_rn(a_lo, lw), __fmul_rn(a_hi_v, gw));
}

// ---------------------------------------------------------------------------
// K3: mask + IDWT + transpose-out. REC_LO[u]=DEC_LO[15-u];
// REC_HI[u]=(u odd?-:+)DEC_LO[u]. All coeff indices in-bounds for T=4096.
// Block: 256 thr, (b, 64-c, 64-s). float4 loads & stores (4 ch / thread).
// ---------------------------------------------------------------------------
#define K3_PITCH 68 // float4-aligned LDS pitch

__global__ __launch_bounds__(256) void k_idwt(const float* __restrict__ lo,
                                              const float* __restrict__ hi,
                                              const float* __restrict__ thr,
                                              float* __restrict__ out) {
  __shared__ float s_ca[40 * K3_PITCH];
  __shared__ float s_cd[40 * K3_PITCH];
  __shared__ float s_thr[64];
  const int s0 = blockIdx.x * 64;
  const int bc = blockIdx.y;
  const int b = bc >> 3;
  const int c0 = (bc & 7) * 64;
  const int m0 = s0 >> 1;
  const int tid = threadIdx.x;

  if (tid < 64) s_thr[tid] = thr[b * C_LEN + c0 + tid];
  __syncthreads();

  // stage 40 coeffs x 64 ch; float4 row loads (m0+40 <= 2056 <= pitch: the
  // over-read hits row padding, only mm=39 which is never used in compute)
  for (int r = tid; r < 64 * 10; r += 256) {
    int cc = r / 10;
    int m4 = r % 10;
    size_t base = (size_t)(b * C_LEN + c0 + cc) * W_PITCH + m0 + m4 * 4;
    float4 a = *(const float4*)(lo + base);
    float4 d = *(const float4*)(hi + base);
    float th = s_thr[cc];
    d.x = (__fmul_rn(d.x, d.x) > th) ? d.x : 0.f;
    d.y = (__fmul_rn(d.y, d.y) > th) ? d.y : 0.f;
    d.z = (__fmul_rn(d.z, d.z) > th) ? d.z : 0.f;
    d.w = (__fmul_rn(d.w, d.w) > th) ? d.w : 0.f;
    int li = (m4 * 4) * K3_PITCH + cc;
    s_ca[li] = a.x;
    s_ca[li + K3_PITCH] = a.y;
    s_ca[li + 2 * K3_PITCH] = a.z;
    s_ca[li + 3 * K3_PITCH] = a.w;
    s_cd[li] = d.x;
    s_cd[li + K3_PITCH] = d.y;
    s_cd[li + 2 * K3_PITCH] = d.z;
    s_cd[li + 3 * K3_PITCH] = d.w;
  }
  __syncthreads();

  const int cg = (tid & 15) * 4; // 4 consecutive channels per thread
  const int sb = (tid >> 4) * 4; // 4 consecutive s per thread
#pragma unroll
  for (int k = 0; k < 4; ++k) {
    const int ss = sb + k;
    const int par = ss & 1;
    float4 acc = {0.f, 0.f, 0.f, 0.f};
#pragma unroll
    for (int j = 0; j < 8; ++j) {
      const int u = 2 * j + par;
      const int mm = (ss + 14 - u) >> 1;
      const float rl = c_dec_lo[15 - u];
      const float rh = (u & 1) ? -c_dec_lo[u] : c_dec_lo[u];
      float4 ca = *(const float4*)&s_ca[mm * K3_PITCH + cg];
      float4 cd = *(const float4*)&s_cd[mm * K3_PITCH + cg];
      acc.x = fmaf(rl, ca.x, acc.x);
      acc.y = fmaf(rl, ca.y, acc.y);
      acc.z = fmaf(rl, ca.z, acc.z);
      acc.w = fmaf(rl, ca.w, acc.w);
      acc.x = fmaf(rh, cd.x, acc.x);
      acc.y = fmaf(rh, cd.y, acc.y);
      acc.z = fmaf(rh, cd.z, acc.z);
      acc.w = fmaf(rh, cd.w, acc.w);
    }
    *(float4*)(out + ((size_t)b * T_LEN + s0 + ss) * C_LEN + c0 + cg) = acc;
  }
}

// ---------------------------------------------------------------------------
extern "C" void kernel_launch(void* const* d_in, const int* in_sizes, int n_in,
                              void* d_out, int out_size, void* d_ws,
                              size_t ws_size, hipStream_t stream) {
  const float* x = (const float*)d_in[0];
  const float* qp = (const float*)d_in[1];
  float* out = (float*)d_out;

  // workspace: lo | hi | thr  (~258 MiB)
  float* lo = (float*)d_ws;
  float* hi = lo + (size_t)ROWS * W_PITCH;
  float* thr = hi + (size_t)ROWS * W_PITCH;

  dim3 g1((W_LEN + K1_WT - 1) / K1_WT, 256); // 65 x 256
  k_dwt<<<g1, 256, 0, stream>>>(x, lo, hi);

  k_thresh<<<dim3(ROWS), 256, 0, stream>>>(hi, qp, thr);

  dim3 g3(T_LEN / 64, 256); // 64 x 256
  k_idwt<<<g3, 256, 0, stream>>>(lo, hi, thr, out);
}